// Round 1
// baseline (498.101 us; speedup 1.0000x reference)
//
#include <hip/hip_runtime.h>
#include <hip/hip_bf16.h>
#include <stdint.h>

// ---------------------------------------------------------------------------
// Attention block, B=4 N=2048 C=1024 H=16 D=64, bf16 MFMA pipeline:
//   cvt(x,w*) -> gemm_bt(QKV fused, scale Q) -> flash attn -> gemm_bt(+bias)
// ws layout (bf16/ushort elems):
//   Xb[8192*1024] | Wqkv[3072*1024] | Wob[1024*1024] | Qkv[8192*3072]
//   Obuf reuses Xb (dead after QKV gemm).  Total ~72 MB.
// ---------------------------------------------------------------------------

#define GAS __attribute__((address_space(1)))
#define LAS __attribute__((address_space(3)))

typedef __attribute__((ext_vector_type(8))) short v8s;   // 8 x bf16 (4 VGPR)
typedef __attribute__((ext_vector_type(4))) float v4f;   // mfma accumulator

__device__ __forceinline__ unsigned short f2bf(float f) {
  unsigned int u = __builtin_bit_cast(unsigned int, f);
  return (unsigned short)((u + 0x7FFFu + ((u >> 16) & 1u)) >> 16);  // RNE
}

// global -> LDS direct DMA, 16B/lane. LDS dest must be wave-uniform base;
// HW adds lane*16. Generic->AS3 via 32-bit truncation (low 32 bits = LDS off).
__device__ __forceinline__ void gld_lds16(const void* g, void* l) {
  __builtin_amdgcn_global_load_lds((GAS void*)(uintptr_t)g,
                                   (LAS void*)(uint32_t)(uintptr_t)l,
                                   16, 0, 0);
}

// ---------------------------------------------------------------------------
__global__ void cvt_f32_bf16(const float* __restrict__ src,
                             unsigned short* __restrict__ dst, int n4) {
  int i = blockIdx.x * blockDim.x + threadIdx.x;
  const int stride = gridDim.x * blockDim.x;
  for (; i < n4; i += stride) {
    float4 f = ((const float4*)src)[i];
    ushort4 u;
    u.x = f2bf(f.x); u.y = f2bf(f.y); u.z = f2bf(f.z); u.w = f2bf(f.w);
    ((ushort4*)dst)[i] = u;
  }
}

// ---------------------------------------------------------------------------
// C[m][o] = sum_c A[m][c] * B[o][c]   (B^T layout, both row-major along K)
// 128x128 tile, BK=64, 4 waves each 64x64 (4x4 of 16x16x32 frags).
// OUTMODE 0: bf16 out, cols < scaleCols scaled by scaleVal.
// OUTMODE 1: fp32 out + bias.
template<int OUTMODE>
__global__ __launch_bounds__(256)
void gemm_bt(const unsigned short* __restrict__ A,
             const unsigned short* __restrict__ Bm,
             void* __restrict__ Cout, const float* __restrict__ bias,
             int M, int N, int K, int scaleCols, float scaleVal)
{
  __shared__ unsigned short sA[128 * 64];   // [128 rows][64 k] bf16, 16KB
  __shared__ unsigned short sB[128 * 64];

  const int tid  = threadIdx.x;
  const int lane = tid & 63;
  const int w    = tid >> 6;
  const int g    = lane >> 4;
  const int r16  = lane & 15;
  const long bm  = (long)blockIdx.y * 128;
  const long bn  = (long)blockIdx.x * 128;
  const int  wm  = (w >> 1) * 64;
  const int  wn  = (w & 1) * 64;

  v4f acc[4][4] = {};

  for (int k0 = 0; k0 < K; k0 += 64) {
    // stage: 16 instrs per tile, 4 per wave; 8 rows (1KB) per instr
    #pragma unroll
    for (int t4 = 0; t4 < 4; ++t4) {
      const int t   = t4 * 4 + w;
      const int row = t * 8 + (lane >> 3);
      const long co = (long)k0 + (lane & 7) * 8;
      gld_lds16(A  + (bm + row) * K + co, (char*)sA + t * 1024);
      gld_lds16(Bm + (bn + row) * K + co, (char*)sB + t * 1024);
    }
    __syncthreads();

    v8s af[4][2], bf[4][2];
    #pragma unroll
    for (int m = 0; m < 4; ++m)
      #pragma unroll
      for (int kk = 0; kk < 2; ++kk)
        af[m][kk] = *(const v8s*)(sA + (wm + m*16 + r16)*64 + kk*32 + g*8);
    #pragma unroll
    for (int n = 0; n < 4; ++n)
      #pragma unroll
      for (int kk = 0; kk < 2; ++kk)
        bf[n][kk] = *(const v8s*)(sB + (wn + n*16 + r16)*64 + kk*32 + g*8);
    #pragma unroll
    for (int kk = 0; kk < 2; ++kk)
      #pragma unroll
      for (int m = 0; m < 4; ++m)
        #pragma unroll
        for (int n = 0; n < 4; ++n)
          acc[m][n] = __builtin_amdgcn_mfma_f32_16x16x32_bf16(
              af[m][kk], bf[n][kk], acc[m][n], 0, 0, 0);
    __syncthreads();
  }

  // epilogue: C row = (lane>>4)*4 + reg, col = lane&15  (verified layout)
  #pragma unroll
  for (int m = 0; m < 4; ++m) {
    #pragma unroll
    for (int n = 0; n < 4; ++n) {
      const long row0 = bm + wm + m*16 + g*4;
      const long col  = bn + wn + n*16 + r16;
      if constexpr (OUTMODE == 0) {
        unsigned short* Cb = (unsigned short*)Cout;
        const float sc = (col < scaleCols) ? scaleVal : 1.0f;
        #pragma unroll
        for (int r = 0; r < 4; ++r)
          Cb[(row0 + r) * N + col] = f2bf(acc[m][n][r] * sc);
      } else {
        float* Cf = (float*)Cout;
        const float bv = bias[col];
        #pragma unroll
        for (int r = 0; r < 4; ++r)
          Cf[(row0 + r) * N + col] = acc[m][n][r] + bv;
      }
    }
  }
}

// ---------------------------------------------------------------------------
// Flash attention. Qkv rows = b*2048+n, cols: Q=[0,1024) K=[1024,2048) V=[2048,3072),
// head h at col offset h*64. Block: 128 Q rows, 4 waves x 32 rows. KVBLK=64.
__global__ __launch_bounds__(256)
void attn_fwd(const unsigned short* __restrict__ Qkv,
              unsigned short* __restrict__ O)
{
  __shared__ unsigned short sK [64 * 64];     // [kv j][d]   8KB
  __shared__ unsigned short sVT[64 * 64];     // [d][kv j]   8KB (transposed)
  __shared__ unsigned short sP [4][32 * 64];  // per-wave P  16KB

  const int tid  = threadIdx.x;
  const int lane = tid & 63;
  const int w    = tid >> 6;
  const int g    = lane >> 4;
  const int r16  = lane & 15;
  const int b  = blockIdx.z;
  const int h  = blockIdx.y;
  const int qb = blockIdx.x;
  const long rowQ0  = (long)b * 2048 + qb * 128;
  const long kvbase = (long)b * 2048;
  const int ld = 3072;

  // Q fragments in registers for the whole kernel (SCALE already folded in)
  v8s qf[2][2];
  #pragma unroll
  for (int m = 0; m < 2; ++m)
    #pragma unroll
    for (int kk = 0; kk < 2; ++kk)
      qf[m][kk] = *(const v8s*)(Qkv + (rowQ0 + w*32 + m*16 + r16) * ld
                                + h*64 + kk*32 + g*8);

  v4f oacc[2][4] = {};
  float mrow[2][4], lrow[2][4];
  #pragma unroll
  for (int m = 0; m < 2; ++m)
    #pragma unroll
    for (int r = 0; r < 4; ++r) { mrow[m][r] = -__builtin_inff(); lrow[m][r] = 0.0f; }

  for (int kv0 = 0; kv0 < 2048; kv0 += 64) {
    // stage K tile [64][64] via direct DMA (2 instrs/wave)
    #pragma unroll
    for (int t2 = 0; t2 < 2; ++t2) {
      const int t   = t2 * 4 + w;
      const int row = t * 8 + (lane >> 3);
      gld_lds16(Qkv + (kvbase + kv0 + row) * ld + 1024 + h*64 + (lane & 7) * 8,
                (char*)sK + t * 1024);
    }
    // stage V transposed (reg round-trip; scatter can't use global_load_lds)
    {
      const int j  = tid >> 2;
      const int d0 = (tid & 3) * 16;
      const unsigned short* sv = Qkv + (kvbase + kv0 + j) * ld + 2048 + h*64 + d0;
      v8s v0 = *(const v8s*)sv;
      v8s v1 = *(const v8s*)(sv + 8);
      #pragma unroll
      for (int e = 0; e < 8; ++e) {
        sVT[(d0 + e)     * 64 + j] = (unsigned short)v0[e];
        sVT[(d0 + 8 + e) * 64 + j] = (unsigned short)v1[e];
      }
    }
    __syncthreads();

    // S = Q K^T  (B^T pattern: contraction along d, both row-major in d)
    v4f sacc[2][4] = {};
    v8s kf[4][2];
    #pragma unroll
    for (int n = 0; n < 4; ++n)
      #pragma unroll
      for (int kk = 0; kk < 2; ++kk)
        kf[n][kk] = *(const v8s*)(sK + (n*16 + r16)*64 + kk*32 + g*8);
    #pragma unroll
    for (int kk = 0; kk < 2; ++kk)
      #pragma unroll
      for (int m = 0; m < 2; ++m)
        #pragma unroll
        for (int n = 0; n < 4; ++n)
          sacc[m][n] = __builtin_amdgcn_mfma_f32_16x16x32_bf16(
              qf[m][kk], kf[n][kk], sacc[m][n], 0, 0, 0);

    // online softmax: lane owns rows m*16 + g*4 + r; 64 cols live in
    // {4 n-frags} x {16 lanes of same g}; xor<16 stays within the g-group.
    #pragma unroll
    for (int m = 0; m < 2; ++m) {
      #pragma unroll
      for (int r = 0; r < 4; ++r) {
        float mx = fmaxf(fmaxf(sacc[m][0][r], sacc[m][1][r]),
                         fmaxf(sacc[m][2][r], sacc[m][3][r]));
        #pragma unroll
        for (int off = 1; off < 16; off <<= 1)
          mx = fmaxf(mx, __shfl_xor(mx, off));
        const float mold  = mrow[m][r];
        const float mnew  = fmaxf(mold, mx);
        const float alpha = __expf(mold - mnew);   // exp(-inf)=0 first iter
        mrow[m][r] = mnew;
        float rs = 0.0f;
        #pragma unroll
        for (int n = 0; n < 4; ++n) {
          const float p = __expf(sacc[m][n][r] - mnew);
          sacc[m][n][r] = p;
          rs += p;
        }
        #pragma unroll
        for (int off = 1; off < 16; off <<= 1)
          rs += __shfl_xor(rs, off);
        lrow[m][r] = lrow[m][r] * alpha + rs;
        #pragma unroll
        for (int n = 0; n < 4; ++n)
          oacc[m][n][r] *= alpha;
      }
    }

    // P: C-frag layout -> LDS -> A-frag layout (wave-private, no barrier)
    unsigned short* pb = &sP[w][0];
    #pragma unroll
    for (int m = 0; m < 2; ++m)
      #pragma unroll
      for (int n = 0; n < 4; ++n)
        #pragma unroll
        for (int r = 0; r < 4; ++r)
          pb[(m*16 + g*4 + r)*64 + n*16 + r16] = f2bf(sacc[m][n][r]);
    asm volatile("s_waitcnt lgkmcnt(0)" ::: "memory");

    // O += P V   (A = P rows, B = V^T so k=j is contiguous -> ds_read_b128)
    v8s pf[2][2], vf[4][2];
    #pragma unroll
    for (int m = 0; m < 2; ++m)
      #pragma unroll
      for (int kk = 0; kk < 2; ++kk)
        pf[m][kk] = *(const v8s*)(pb + (m*16 + r16)*64 + kk*32 + g*8);
    #pragma unroll
    for (int n = 0; n < 4; ++n)
      #pragma unroll
      for (int kk = 0; kk < 2; ++kk)
        vf[n][kk] = *(const v8s*)(sVT + (n*16 + r16)*64 + kk*32 + g*8);
    #pragma unroll
    for (int kk = 0; kk < 2; ++kk)
      #pragma unroll
      for (int m = 0; m < 2; ++m)
        #pragma unroll
        for (int n = 0; n < 4; ++n)
          oacc[m][n] = __builtin_amdgcn_mfma_f32_16x16x32_bf16(
              pf[m][kk], vf[n][kk], oacc[m][n], 0, 0, 0);
    __syncthreads();   // protect sK/sVT before next stage
  }

  #pragma unroll
  for (int m = 0; m < 2; ++m) {
    #pragma unroll
    for (int n = 0; n < 4; ++n) {
      const long row0 = rowQ0 + w*32 + m*16 + g*4;
      const int  col  = h*64 + n*16 + r16;
      #pragma unroll
      for (int r = 0; r < 4; ++r)
        O[(row0 + r) * 1024 + col] = f2bf(oacc[m][n][r] / lrow[m][r]);
    }
  }
}

// ---------------------------------------------------------------------------
extern "C" void kernel_launch(void* const* d_in, const int* in_sizes, int n_in,
                              void* d_out, int out_size, void* d_ws, size_t ws_size,
                              hipStream_t stream)
{
  const float* x  = (const float*)d_in[0];
  const float* wq = (const float*)d_in[1];
  const float* wk = (const float*)d_in[2];
  const float* wv = (const float*)d_in[3];
  const float* wo = (const float*)d_in[4];
  const float* bo = (const float*)d_in[5];

  unsigned short* Xb   = (unsigned short*)d_ws;              // 8192*1024
  unsigned short* Wqkv = Xb   + (size_t)8192 * 1024;         // 3072*1024
  unsigned short* Wob  = Wqkv + (size_t)3072 * 1024;         // 1024*1024
  unsigned short* Qkv  = Wob  + (size_t)1024 * 1024;         // 8192*3072
  unsigned short* Obuf = Xb;                                 // reuse (Xb dead)
  float* out = (float*)d_out;

  cvt_f32_bf16<<<2048, 256, 0, stream>>>(x,  Xb,   8192 * 1024 / 4);
  cvt_f32_bf16<<<512,  256, 0, stream>>>(wq, Wqkv,              1024 * 1024 / 4);
  cvt_f32_bf16<<<512,  256, 0, stream>>>(wk, Wqkv + 1024*1024,  1024 * 1024 / 4);
  cvt_f32_bf16<<<512,  256, 0, stream>>>(wv, Wqkv + 2*1024*1024,1024 * 1024 / 4);
  cvt_f32_bf16<<<512,  256, 0, stream>>>(wo, Wob,               1024 * 1024 / 4);

  // QKV: M=8192 N=3072 K=1024; scale Q cols (0..1023) by D^-0.5 = 0.125
  gemm_bt<0><<<dim3(24, 64), 256, 0, stream>>>(Xb, Wqkv, Qkv, nullptr,
                                               8192, 3072, 1024, 1024, 0.125f);
  attn_fwd<<<dim3(16, 16, 4), 256, 0, stream>>>(Qkv, Obuf);
  // out = O @ wo^T + bo, fp32
  gemm_bt<1><<<dim3(8, 64), 256, 0, stream>>>(Obuf, Wob, out, bo,
                                              8192, 1024, 1024, 0, 1.0f);
}

// Round 3
// 385.873 us; speedup vs baseline: 1.2908x; 1.2908x over previous
//
#include <hip/hip_runtime.h>
#include <hip/hip_bf16.h>
#include <stdint.h>

// ---------------------------------------------------------------------------
// Attention block, B=4 N=2048 C=1024 H=16 D=64, bf16 MFMA pipeline:
//   cvt(x,w*) -> gemm_bt(QKV fused, scale Q by 0.125*log2e) -> flash attn
//   (exp2 domain, swizzled LDS) -> gemm_bt(+bias)
// ---------------------------------------------------------------------------

#define GAS __attribute__((address_space(1)))
#define LAS __attribute__((address_space(3)))

typedef __attribute__((ext_vector_type(8))) short v8s;   // 8 x bf16 (4 VGPR)
typedef __attribute__((ext_vector_type(4))) float v4f;   // mfma accumulator

__device__ __forceinline__ unsigned short f2bf(float f) {
  __hip_bfloat16 h = __float2bfloat16(f);   // RNE, HW cvt on gfx950
  return __builtin_bit_cast(unsigned short, h);
}

__device__ __forceinline__ float fexp2(float x) {
#if __has_builtin(__builtin_amdgcn_exp2f)
  return __builtin_amdgcn_exp2f(x);         // v_exp_f32 (native exp2)
#else
  return __expf(x * 0.6931471805599453f);
#endif
}

// global -> LDS direct DMA, 16B/lane. LDS dest wave-uniform base; HW adds lane*16.
__device__ __forceinline__ void gld_lds16(const void* g, void* l) {
  __builtin_amdgcn_global_load_lds((GAS void*)(uintptr_t)g,
                                   (LAS void*)(uint32_t)(uintptr_t)l,
                                   16, 0, 0);
}

// ---------------------------------------------------------------------------
__global__ void cvt_f32_bf16(const float* __restrict__ src,
                             unsigned short* __restrict__ dst, int n4) {
  int i = blockIdx.x * blockDim.x + threadIdx.x;
  const int stride = gridDim.x * blockDim.x;
  for (; i < n4; i += stride) {
    float4 f = ((const float4*)src)[i];
    ushort4 u;
    u.x = f2bf(f.x); u.y = f2bf(f.y); u.z = f2bf(f.z); u.w = f2bf(f.w);
    ((ushort4*)dst)[i] = u;
  }
}

// ---------------------------------------------------------------------------
// C[m][o] = sum_c A[m][c] * B[o][c]   (B^T layout). 128x128 tile, BK=64,
// 4 waves each 64x64. OUTMODE 0: bf16 out, cols<scaleCols scaled.
// OUTMODE 1: fp32 out + bias.
template<int OUTMODE>
__global__ __launch_bounds__(256)
void gemm_bt(const unsigned short* __restrict__ A,
             const unsigned short* __restrict__ Bm,
             void* __restrict__ Cout, const float* __restrict__ bias,
             int M, int N, int K, int scaleCols, float scaleVal)
{
  __shared__ unsigned short sA[128 * 64];
  __shared__ unsigned short sB[128 * 64];

  const int tid  = threadIdx.x;
  const int lane = tid & 63;
  const int w    = tid >> 6;
  const int g    = lane >> 4;
  const int r16  = lane & 15;
  const long bm  = (long)blockIdx.y * 128;
  const long bn  = (long)blockIdx.x * 128;
  const int  wm  = (w >> 1) * 64;
  const int  wn  = (w & 1) * 64;

  v4f acc[4][4] = {};

  for (int k0 = 0; k0 < K; k0 += 64) {
    #pragma unroll
    for (int t4 = 0; t4 < 4; ++t4) {
      const int t   = t4 * 4 + w;
      const int row = t * 8 + (lane >> 3);
      const long co = (long)k0 + (lane & 7) * 8;
      gld_lds16(A  + (bm + row) * K + co, (char*)sA + t * 1024);
      gld_lds16(Bm + (bn + row) * K + co, (char*)sB + t * 1024);
    }
    __syncthreads();

    v8s af[4][2], bf[4][2];
    #pragma unroll
    for (int m = 0; m < 4; ++m)
      #pragma unroll
      for (int kk = 0; kk < 2; ++kk)
        af[m][kk] = *(const v8s*)(sA + (wm + m*16 + r16)*64 + kk*32 + g*8);
    #pragma unroll
    for (int n = 0; n < 4; ++n)
      #pragma unroll
      for (int kk = 0; kk < 2; ++kk)
        bf[n][kk] = *(const v8s*)(sB + (wn + n*16 + r16)*64 + kk*32 + g*8);
    #pragma unroll
    for (int kk = 0; kk < 2; ++kk)
      #pragma unroll
      for (int m = 0; m < 4; ++m)
        #pragma unroll
        for (int n = 0; n < 4; ++n)
          acc[m][n] = __builtin_amdgcn_mfma_f32_16x16x32_bf16(
              af[m][kk], bf[n][kk], acc[m][n], 0, 0, 0);
    __syncthreads();
  }

  #pragma unroll
  for (int m = 0; m < 4; ++m) {
    #pragma unroll
    for (int n = 0; n < 4; ++n) {
      const long row0 = bm + wm + m*16 + g*4;
      const long col  = bn + wn + n*16 + r16;
      if constexpr (OUTMODE == 0) {
        unsigned short* Cb = (unsigned short*)Cout;
        const float sc = (col < scaleCols) ? scaleVal : 1.0f;
        #pragma unroll
        for (int r = 0; r < 4; ++r)
          Cb[(row0 + r) * N + col] = f2bf(acc[m][n][r] * sc);
      } else {
        float* Cf = (float*)Cout;
        const float bv = bias[col];
        #pragma unroll
        for (int r = 0; r < 4; ++r)
          Cf[(row0 + r) * N + col] = acc[m][n][r] + bv;
      }
    }
  }
}

// ---------------------------------------------------------------------------
// Flash attention, exp2 domain (Q pre-scaled by 0.125*log2e in QKV GEMM).
// Block: 64 Q rows, 4 waves x 16 rows. KVBLK=128.
// LDS (48KB): sK[128][64] swizzled (chunk^row&7), sVT u32[64][64 jp]
// swizzled (chunk^d&15), sP per-wave [16][128] swizzled (chunk^row).
__global__ __launch_bounds__(256)
void attn_fwd(const unsigned short* __restrict__ Qkv,
              unsigned short* __restrict__ O)
{
  __shared__ unsigned short sK[128 * 64];
  __shared__ unsigned int   sVT32[64 * 64];
  __shared__ unsigned short sP[4][16 * 128];

  const unsigned short* sVTe = (const unsigned short*)sVT32;
  const int tid  = threadIdx.x;
  const int lane = tid & 63;
  const int w    = tid >> 6;
  const int g    = lane >> 4;
  const int r16  = lane & 15;
  const int b  = blockIdx.z;
  const int h  = blockIdx.y;
  const int qb = blockIdx.x;                  // 32 q-blocks of 64 rows
  const long kvbase = (long)b * 2048;
  const long qrow0w = kvbase + qb * 64 + w * 16;   // this wave's 16 q rows
  const int ld = 3072;

  // Q fragments (A-operand): row = r16, k = kk*32 + g*8
  v8s qf[2];
  #pragma unroll
  for (int kk = 0; kk < 2; ++kk)
    qf[kk] = *(const v8s*)(Qkv + (qrow0w + r16) * ld + h*64 + kk*32 + g*8);

  v4f oacc[4] = {};
  float mrow[4], lsum[4];
  #pragma unroll
  for (int r = 0; r < 4; ++r) { mrow[r] = -__builtin_inff(); lsum[r] = 0.0f; }

  for (int kv0 = 0; kv0 < 2048; kv0 += 128) {
    // ---- stage K [128][64] via gld_lds, source pre-swizzled (rule #21) ----
    #pragma unroll
    for (int t4 = 0; t4 < 4; ++t4) {
      const int t    = t4 * 4 + w;
      const int row  = t * 8 + (lane >> 3);
      const int csrc = (lane & 7) ^ ((lane >> 3) & 7);   // chunk ^ (row&7)
      gld_lds16(Qkv + (kvbase + kv0 + row) * ld + 1024 + h*64 + csrc*8,
                (char*)sK + t * 1024);
    }
    // ---- stage V^T: reg round-trip, packed u32 (j-pair) writes ----
    {
      const int jp = lane;            // j pair (2jp, 2jp+1)
      const int d0 = w * 16;
      const unsigned short* vs = Qkv + (kvbase + kv0 + 2*jp) * ld + 2048 + h*64 + d0;
      v8s va0 = *(const v8s*)vs;
      v8s va1 = *(const v8s*)(vs + 8);
      v8s vb0 = *(const v8s*)(vs + ld);
      v8s vb1 = *(const v8s*)(vs + ld + 8);
      #pragma unroll
      for (int e = 0; e < 8; ++e) {
        int d = d0 + e;
        sVT32[d*64 + (((jp >> 2) ^ (d & 15)) << 2) + (jp & 3)] =
            ((unsigned)(unsigned short)vb0[e] << 16) | (unsigned short)va0[e];
        d = d0 + 8 + e;
        sVT32[d*64 + (((jp >> 2) ^ (d & 15)) << 2) + (jp & 3)] =
            ((unsigned)(unsigned short)vb1[e] << 16) | (unsigned short)va1[e];
      }
    }
    __syncthreads();

    // ---- S = Q K^T : S[q=g*4+r][kv=n*16+r16], 16 MFMA ----
    v4f sacc[8] = {};
    #pragma unroll
    for (int n = 0; n < 8; ++n) {
      const int row = n*16 + r16;
      v8s k0 = *(const v8s*)(sK + row*64 + (((0*4+g) ^ (row & 7)) << 3));
      v8s k1 = *(const v8s*)(sK + row*64 + (((1*4+g) ^ (row & 7)) << 3));
      sacc[n] = __builtin_amdgcn_mfma_f32_16x16x32_bf16(qf[0], k0, sacc[n], 0, 0, 0);
      sacc[n] = __builtin_amdgcn_mfma_f32_16x16x32_bf16(qf[1], k1, sacc[n], 0, 0, 0);
    }

    // ---- online softmax (exp2 domain), deferred sum, defer-max THR=8 ----
    float mx[4];
    #pragma unroll
    for (int r = 0; r < 4; ++r) {
      float v = fmaxf(fmaxf(fmaxf(sacc[0][r], sacc[1][r]),
                            fmaxf(sacc[2][r], sacc[3][r])),
                      fmaxf(fmaxf(sacc[4][r], sacc[5][r]),
                            fmaxf(sacc[6][r], sacc[7][r])));
      v = fmaxf(v, __shfl_xor(v, 1));
      v = fmaxf(v, __shfl_xor(v, 2));
      v = fmaxf(v, __shfl_xor(v, 4));
      v = fmaxf(v, __shfl_xor(v, 8));
      mx[r] = v;
    }
    const float need = fmaxf(fmaxf(mx[0] - mrow[0], mx[1] - mrow[1]),
                             fmaxf(mx[2] - mrow[2], mx[3] - mrow[3]));
    if (__any(need > 8.0f)) {
      #pragma unroll
      for (int r = 0; r < 4; ++r) {
        const float mnew  = fmaxf(mrow[r], mx[r]);
        const float alpha = fexp2(mrow[r] - mnew);
        mrow[r] = mnew;
        lsum[r] *= alpha;
        #pragma unroll
        for (int n = 0; n < 4; ++n) oacc[n][r] *= alpha;
      }
    }
    #pragma unroll
    for (int n = 0; n < 8; ++n)
      #pragma unroll
      for (int r = 0; r < 4; ++r) {
        const float p = fexp2(sacc[n][r] - mrow[r]);
        sacc[n][r] = p;
        lsum[r] += p;          // partial over this lane's columns
      }

    // ---- P -> LDS (swizzled), C-frag layout -> A-frag layout ----
    unsigned short* pb = &sP[w][0];
    #pragma unroll
    for (int n = 0; n < 8; ++n) {
      const int col = n*16 + r16;
      const int ch  = col >> 3;
      #pragma unroll
      for (int r = 0; r < 4; ++r) {
        const int row = g*4 + r;
        pb[row*128 + ((ch ^ row) << 3) + (col & 7)] = f2bf(sacc[n][r]);
      }
    }

    // ---- O += P V : A = P[q=r16][j], B = V^T[d=n*16+r16][j], 16 MFMA ----
    #pragma unroll
    for (int kk = 0; kk < 4; ++kk) {
      v8s pf = *(const v8s*)(pb + r16*128 + (((kk*4+g) ^ r16) << 3));
      #pragma unroll
      for (int n = 0; n < 4; ++n) {
        const int d = n*16 + r16;      // d&15 == r16
        v8s vf = *(const v8s*)(sVTe + d*128 + (((kk*4+g) ^ (d & 15)) << 3));
        oacc[n] = __builtin_amdgcn_mfma_f32_16x16x32_bf16(pf, vf, oacc[n], 0, 0, 0);
      }
    }
    __syncthreads();   // protect sK/sVT before next stage
  }

  // ---- epilogue: reduce lsum across the g-group, normalize, write ----
  float rs[4];
  #pragma unroll
  for (int r = 0; r < 4; ++r) {
    float s = lsum[r];
    s += __shfl_xor(s, 1);
    s += __shfl_xor(s, 2);
    s += __shfl_xor(s, 4);
    s += __shfl_xor(s, 8);
    rs[r] = 1.0f / s;
  }
  #pragma unroll
  for (int n = 0; n < 4; ++n) {
    const int col = h*64 + n*16 + r16;
    #pragma unroll
    for (int r = 0; r < 4; ++r)
      O[(qrow0w + g*4 + r) * 1024 + col] = f2bf(oacc[n][r] * rs[r]);
  }
}

// ---------------------------------------------------------------------------
extern "C" void kernel_launch(void* const* d_in, const int* in_sizes, int n_in,
                              void* d_out, int out_size, void* d_ws, size_t ws_size,
                              hipStream_t stream)
{
  const float* x  = (const float*)d_in[0];
  const float* wq = (const float*)d_in[1];
  const float* wk = (const float*)d_in[2];
  const float* wv = (const float*)d_in[3];
  const float* wo = (const float*)d_in[4];
  const float* bo = (const float*)d_in[5];

  unsigned short* Xb   = (unsigned short*)d_ws;              // 8192*1024
  unsigned short* Wqkv = Xb   + (size_t)8192 * 1024;         // 3072*1024
  unsigned short* Wob  = Wqkv + (size_t)3072 * 1024;         // 1024*1024
  unsigned short* Qkv  = Wob  + (size_t)1024 * 1024;         // 8192*3072
  unsigned short* Obuf = Xb;                                 // reuse (Xb dead)
  float* out = (float*)d_out;

  cvt_f32_bf16<<<2048, 256, 0, stream>>>(x,  Xb,   8192 * 1024 / 4);
  cvt_f32_bf16<<<512,  256, 0, stream>>>(wq, Wqkv,              1024 * 1024 / 4);
  cvt_f32_bf16<<<512,  256, 0, stream>>>(wk, Wqkv + 1024*1024,  1024 * 1024 / 4);
  cvt_f32_bf16<<<512,  256, 0, stream>>>(wv, Wqkv + 2*1024*1024,1024 * 1024 / 4);
  cvt_f32_bf16<<<512,  256, 0, stream>>>(wo, Wob,               1024 * 1024 / 4);

  // QKV: M=8192 N=3072 K=1024; Q cols scaled by 0.125 * log2(e)  (exp2 domain)
  gemm_bt<0><<<dim3(24, 64), 256, 0, stream>>>(Xb, Wqkv, Qkv, nullptr,
                                               8192, 3072, 1024, 1024,
                                               0.18033688011112042f);
  attn_fwd<<<dim3(32, 16, 4), 256, 0, stream>>>(Qkv, Obuf);
  gemm_bt<1><<<dim3(8, 64), 256, 0, stream>>>(Obuf, Wob, out, bo,
                                              8192, 1024, 1024, 0, 1.0f);
}

// Round 4
// 383.729 us; speedup vs baseline: 1.2981x; 1.0056x over previous
//
#include <hip/hip_runtime.h>
#include <hip/hip_bf16.h>
#include <stdint.h>

// ---------------------------------------------------------------------------
// Attention block, B=4 N=2048 C=1024 H=16 D=64, bf16 MFMA pipeline:
//   cvt(x,w*) -> gemm_bt(QKV fused, scale Q by 0.125*log2e) -> flash attn
//   (exp2 domain, swizzled LDS, double-buffered async staging) -> gemm_bt(+bias)
// ---------------------------------------------------------------------------

#define GAS __attribute__((address_space(1)))
#define LAS __attribute__((address_space(3)))

typedef __attribute__((ext_vector_type(8))) short v8s;   // 8 x bf16 (4 VGPR)
typedef __attribute__((ext_vector_type(4))) float v4f;   // mfma accumulator

__device__ __forceinline__ unsigned short f2bf(float f) {
  __hip_bfloat16 h = __float2bfloat16(f);   // RNE, HW cvt on gfx950
  return __builtin_bit_cast(unsigned short, h);
}

__device__ __forceinline__ float fexp2(float x) {
#if __has_builtin(__builtin_amdgcn_exp2f)
  return __builtin_amdgcn_exp2f(x);         // v_exp_f32 (native exp2)
#else
  return __expf(x * 0.6931471805599453f);
#endif
}

// global -> LDS direct DMA, 16B/lane. LDS dest wave-uniform base; HW adds lane*16.
__device__ __forceinline__ void gld_lds16(const void* g, void* l) {
  __builtin_amdgcn_global_load_lds((GAS void*)(uintptr_t)g,
                                   (LAS void*)(uint32_t)(uintptr_t)l,
                                   16, 0, 0);
}

// ---------------------------------------------------------------------------
__global__ void cvt_f32_bf16(const float* __restrict__ src,
                             unsigned short* __restrict__ dst, int n4) {
  int i = blockIdx.x * blockDim.x + threadIdx.x;
  const int stride = gridDim.x * blockDim.x;
  for (; i < n4; i += stride) {
    float4 f = ((const float4*)src)[i];
    ushort4 u;
    u.x = f2bf(f.x); u.y = f2bf(f.y); u.z = f2bf(f.z); u.w = f2bf(f.w);
    ((ushort4*)dst)[i] = u;
  }
}

// ---------------------------------------------------------------------------
// C[m][o] = sum_c A[m][c] * B[o][c]   (B^T layout). 128x128 tile, BK=64,
// 4 waves each 64x64. OUTMODE 0: bf16 out, cols<scaleCols scaled.
// OUTMODE 1: fp32 out + bias.
template<int OUTMODE>
__global__ __launch_bounds__(256)
void gemm_bt(const unsigned short* __restrict__ A,
             const unsigned short* __restrict__ Bm,
             void* __restrict__ Cout, const float* __restrict__ bias,
             int M, int N, int K, int scaleCols, float scaleVal)
{
  __shared__ unsigned short sA[128 * 64];
  __shared__ unsigned short sB[128 * 64];

  const int tid  = threadIdx.x;
  const int lane = tid & 63;
  const int w    = tid >> 6;
  const int g    = lane >> 4;
  const int r16  = lane & 15;
  const long bm  = (long)blockIdx.y * 128;
  const long bn  = (long)blockIdx.x * 128;
  const int  wm  = (w >> 1) * 64;
  const int  wn  = (w & 1) * 64;

  v4f acc[4][4] = {};

  for (int k0 = 0; k0 < K; k0 += 64) {
    #pragma unroll
    for (int t4 = 0; t4 < 4; ++t4) {
      const int t   = t4 * 4 + w;
      const int row = t * 8 + (lane >> 3);
      const long co = (long)k0 + (lane & 7) * 8;
      gld_lds16(A  + (bm + row) * K + co, (char*)sA + t * 1024);
      gld_lds16(Bm + (bn + row) * K + co, (char*)sB + t * 1024);
    }
    __syncthreads();

    v8s af[4][2], bf[4][2];
    #pragma unroll
    for (int m = 0; m < 4; ++m)
      #pragma unroll
      for (int kk = 0; kk < 2; ++kk)
        af[m][kk] = *(const v8s*)(sA + (wm + m*16 + r16)*64 + kk*32 + g*8);
    #pragma unroll
    for (int n = 0; n < 4; ++n)
      #pragma unroll
      for (int kk = 0; kk < 2; ++kk)
        bf[n][kk] = *(const v8s*)(sB + (wn + n*16 + r16)*64 + kk*32 + g*8);
    #pragma unroll
    for (int kk = 0; kk < 2; ++kk)
      #pragma unroll
      for (int m = 0; m < 4; ++m)
        #pragma unroll
        for (int n = 0; n < 4; ++n)
          acc[m][n] = __builtin_amdgcn_mfma_f32_16x16x32_bf16(
              af[m][kk], bf[n][kk], acc[m][n], 0, 0, 0);
    __syncthreads();
  }

  #pragma unroll
  for (int m = 0; m < 4; ++m) {
    #pragma unroll
    for (int n = 0; n < 4; ++n) {
      const long row0 = bm + wm + m*16 + g*4;
      const long col  = bn + wn + n*16 + r16;
      if constexpr (OUTMODE == 0) {
        unsigned short* Cb = (unsigned short*)Cout;
        const float sc = (col < scaleCols) ? scaleVal : 1.0f;
        #pragma unroll
        for (int r = 0; r < 4; ++r)
          Cb[(row0 + r) * N + col] = f2bf(acc[m][n][r] * sc);
      } else {
        float* Cf = (float*)Cout;
        const float bv = bias[col];
        #pragma unroll
        for (int r = 0; r < 4; ++r)
          Cf[(row0 + r) * N + col] = acc[m][n][r] + bv;
      }
    }
  }
}

// ---------------------------------------------------------------------------
// Flash attention, exp2 domain (Q pre-scaled by 0.125*log2e in QKV GEMM).
// Block: 64 Q rows, 4 waves x 16 rows. KVBLK=128, double-buffered K/V.
// Schedule per tile t (ONE barrier):
//   vmcnt(0) drain -> write V^T[cur] from regs -> __syncthreads ->
//   issue K-DMA[nxt] + V-loads[nxt] -> QK^T[cur] -> softmax -> PV[cur]
// LDS (80KB): sK[2][128][64] swz(ch^row&7), sVT[2] u32[64][64jp] swz(ch^d&15),
// sP per-wave [16][128] swz(ch^row).
__global__ __launch_bounds__(256)
void attn_fwd(const unsigned short* __restrict__ Qkv,
              unsigned short* __restrict__ O)
{
  __shared__ unsigned short sK[2][128 * 64];
  __shared__ unsigned int   sVT32[2][64 * 64];
  __shared__ unsigned short sP[4][16 * 128];

  const int tid  = threadIdx.x;
  const int lane = tid & 63;
  const int w    = tid >> 6;
  const int g    = lane >> 4;
  const int r16  = lane & 15;
  const int b  = blockIdx.z;
  const int h  = blockIdx.y;
  const int qb = blockIdx.x;                  // 32 q-blocks of 64 rows
  const long kvbase = (long)b * 2048;
  const long qrow0w = kvbase + qb * 64 + w * 16;   // this wave's 16 q rows
  const int ld = 3072;

  // precomputed staging address parts
  const int  rowk = w * 8 + (lane >> 3);                    // + t4*32
  const int  csrc = (lane & 7) ^ ((lane >> 3) & 7);         // chunk ^ (row&7)
  const unsigned short* Kb = Qkv + 1024 + h*64 + csrc*8;    // + (kvrow)*ld
  const int  jp = lane, d0v = w * 16;
  const unsigned short* Vb = Qkv + 2048 + h*64 + d0v;       // + (kv0+2jp)*ld

  // Q fragments (A-operand): row = r16, k = kk*32 + g*8
  v8s qf[2];
  #pragma unroll
  for (int kk = 0; kk < 2; ++kk)
    qf[kk] = *(const v8s*)(Qkv + (qrow0w + r16) * ld + h*64 + kk*32 + g*8);

  v4f oacc[4] = {};
  float mrow[4], lsum[4];
  #pragma unroll
  for (int r = 0; r < 4; ++r) { mrow[r] = -__builtin_inff(); lsum[r] = 0.0f; }

  // ---- prologue: stage tile 0 ----
  v8s vreg[4];
  #pragma unroll
  for (int t4 = 0; t4 < 4; ++t4)
    gld_lds16(Kb + (kvbase + t4*32 + rowk) * ld,
              (char*)sK[0] + (t4*4 + w) * 1024);
  {
    const unsigned short* vs = Vb + (kvbase + 2*jp) * ld;
    vreg[0] = *(const v8s*)vs;
    vreg[1] = *(const v8s*)(vs + 8);
    vreg[2] = *(const v8s*)(vs + ld);
    vreg[3] = *(const v8s*)(vs + ld + 8);
  }

  for (int t = 0; t < 16; ++t) {
    unsigned short* sKc  = &sK[t & 1][0];
    unsigned int*   sVTc = &sVT32[t & 1][0];
    const unsigned short* sVTe = (const unsigned short*)sVTc;

    // drain this buffer's K-DMA + V loads, then publish V^T
    asm volatile("s_waitcnt vmcnt(0)" ::: "memory");
    #pragma unroll
    for (int e = 0; e < 8; ++e) {
      int d = d0v + e;
      sVTc[d*64 + (((jp >> 2) ^ (d & 15)) << 2) + (jp & 3)] =
          ((unsigned)(unsigned short)vreg[2][e] << 16) | (unsigned short)vreg[0][e];
      d = d0v + 8 + e;
      sVTc[d*64 + (((jp >> 2) ^ (d & 15)) << 2) + (jp & 3)] =
          ((unsigned)(unsigned short)vreg[3][e] << 16) | (unsigned short)vreg[1][e];
    }
    __syncthreads();

    // issue next tile's staging (lands during this tile's compute)
    if (t < 15) {
      const long kvn = kvbase + (long)(t + 1) * 128;
      char* sKn = (char*)&sK[(t + 1) & 1][0];
      #pragma unroll
      for (int t4 = 0; t4 < 4; ++t4)
        gld_lds16(Kb + (kvn + t4*32 + rowk) * ld, sKn + (t4*4 + w) * 1024);
      const unsigned short* vs = Vb + (kvn + 2*jp) * ld;
      vreg[0] = *(const v8s*)vs;
      vreg[1] = *(const v8s*)(vs + 8);
      vreg[2] = *(const v8s*)(vs + ld);
      vreg[3] = *(const v8s*)(vs + ld + 8);
    }

    // ---- S = Q K^T : S[q=g*4+r][kv=n*16+r16], 16 MFMA ----
    v4f sacc[8] = {};
    __builtin_amdgcn_s_setprio(1);
    #pragma unroll
    for (int n = 0; n < 8; ++n) {
      const int row = n*16 + r16;
      v8s k0 = *(const v8s*)(sKc + row*64 + ((g ^ (row & 7)) << 3));
      v8s k1 = *(const v8s*)(sKc + row*64 + (((4 + g) ^ (row & 7)) << 3));
      sacc[n] = __builtin_amdgcn_mfma_f32_16x16x32_bf16(qf[0], k0, sacc[n], 0, 0, 0);
      sacc[n] = __builtin_amdgcn_mfma_f32_16x16x32_bf16(qf[1], k1, sacc[n], 0, 0, 0);
    }
    __builtin_amdgcn_s_setprio(0);

    // ---- online softmax (exp2 domain), deferred sum, defer-max THR=8 ----
    float mx[4];
    #pragma unroll
    for (int r = 0; r < 4; ++r) {
      float v = fmaxf(fmaxf(fmaxf(sacc[0][r], sacc[1][r]),
                            fmaxf(sacc[2][r], sacc[3][r])),
                      fmaxf(fmaxf(sacc[4][r], sacc[5][r]),
                            fmaxf(sacc[6][r], sacc[7][r])));
      v = fmaxf(v, __shfl_xor(v, 1));
      v = fmaxf(v, __shfl_xor(v, 2));
      v = fmaxf(v, __shfl_xor(v, 4));
      v = fmaxf(v, __shfl_xor(v, 8));
      mx[r] = v;
    }
    const float need = fmaxf(fmaxf(mx[0] - mrow[0], mx[1] - mrow[1]),
                             fmaxf(mx[2] - mrow[2], mx[3] - mrow[3]));
    if (__any(need > 8.0f)) {
      #pragma unroll
      for (int r = 0; r < 4; ++r) {
        const float mnew  = fmaxf(mrow[r], mx[r]);
        const float alpha = fexp2(mrow[r] - mnew);
        mrow[r] = mnew;
        lsum[r] *= alpha;
        #pragma unroll
        for (int n = 0; n < 4; ++n) oacc[n][r] *= alpha;
      }
    }
    #pragma unroll
    for (int n = 0; n < 8; ++n)
      #pragma unroll
      for (int r = 0; r < 4; ++r) {
        const float p = fexp2(sacc[n][r] - mrow[r]);
        sacc[n][r] = p;
        lsum[r] += p;          // partial over this lane's columns
      }

    // ---- P -> LDS (swizzled), C-frag layout -> A-frag layout ----
    unsigned short* pb = &sP[w][0];
    #pragma unroll
    for (int n = 0; n < 8; ++n) {
      const int col = n*16 + r16;
      const int ch  = col >> 3;
      #pragma unroll
      for (int r = 0; r < 4; ++r) {
        const int row = g*4 + r;
        pb[row*128 + ((ch ^ row) << 3) + (col & 7)] = f2bf(sacc[n][r]);
      }
    }

    // ---- O += P V : A = P[q=r16][j], B = V^T[d=n*16+r16][j], 16 MFMA ----
    // (DS ops within a wave are ordered; sP is wave-private, no barrier)
    __builtin_amdgcn_s_setprio(1);
    #pragma unroll
    for (int kk = 0; kk < 4; ++kk) {
      v8s pf = *(const v8s*)(pb + r16*128 + (((kk*4 + g) ^ r16) << 3));
      #pragma unroll
      for (int n = 0; n < 4; ++n) {
        const int d = n*16 + r16;      // d&15 == r16
        v8s vf = *(const v8s*)(sVTe + d*128 + (((kk*4 + g) ^ (d & 15)) << 3));
        oacc[n] = __builtin_amdgcn_mfma_f32_16x16x32_bf16(pf, vf, oacc[n], 0, 0, 0);
      }
    }
    __builtin_amdgcn_s_setprio(0);
  }

  // ---- epilogue: reduce lsum across the g-group, normalize, write ----
  float rs[4];
  #pragma unroll
  for (int r = 0; r < 4; ++r) {
    float s = lsum[r];
    s += __shfl_xor(s, 1);
    s += __shfl_xor(s, 2);
    s += __shfl_xor(s, 4);
    s += __shfl_xor(s, 8);
    rs[r] = 1.0f / s;
  }
  #pragma unroll
  for (int n = 0; n < 4; ++n) {
    const int col = h*64 + n*16 + r16;
    #pragma unroll
    for (int r = 0; r < 4; ++r)
      O[(qrow0w + g*4 + r) * 1024 + col] = f2bf(oacc[n][r] * rs[r]);
  }
}

// ---------------------------------------------------------------------------
extern "C" void kernel_launch(void* const* d_in, const int* in_sizes, int n_in,
                              void* d_out, int out_size, void* d_ws, size_t ws_size,
                              hipStream_t stream)
{
  const float* x  = (const float*)d_in[0];
  const float* wq = (const float*)d_in[1];
  const float* wk = (const float*)d_in[2];
  const float* wv = (const float*)d_in[3];
  const float* wo = (const float*)d_in[4];
  const float* bo = (const float*)d_in[5];

  unsigned short* Xb   = (unsigned short*)d_ws;              // 8192*1024
  unsigned short* Wqkv = Xb   + (size_t)8192 * 1024;         // 3072*1024
  unsigned short* Wob  = Wqkv + (size_t)3072 * 1024;         // 1024*1024
  unsigned short* Qkv  = Wob  + (size_t)1024 * 1024;         // 8192*3072
  unsigned short* Obuf = Xb;                                 // reuse (Xb dead)
  float* out = (float*)d_out;

  cvt_f32_bf16<<<2048, 256, 0, stream>>>(x,  Xb,   8192 * 1024 / 4);
  cvt_f32_bf16<<<512,  256, 0, stream>>>(wq, Wqkv,              1024 * 1024 / 4);
  cvt_f32_bf16<<<512,  256, 0, stream>>>(wk, Wqkv + 1024*1024,  1024 * 1024 / 4);
  cvt_f32_bf16<<<512,  256, 0, stream>>>(wv, Wqkv + 2*1024*1024,1024 * 1024 / 4);
  cvt_f32_bf16<<<512,  256, 0, stream>>>(wo, Wob,               1024 * 1024 / 4);

  // QKV: M=8192 N=3072 K=1024; Q cols scaled by 0.125 * log2(e)  (exp2 domain)
  gemm_bt<0><<<dim3(24, 64), 256, 0, stream>>>(Xb, Wqkv, Qkv, nullptr,
                                               8192, 3072, 1024, 1024,
                                               0.18033688011112042f);
  attn_fwd<<<dim3(32, 16, 4), 256, 0, stream>>>(Qkv, Obuf);
  gemm_bt<1><<<dim3(8, 64), 256, 0, stream>>>(Obuf, Wob, out, bo,
                                              8192, 1024, 1024, 0, 1.0f);
}